// Round 1
// baseline (6857.377 us; speedup 1.0000x reference)
//
#include <hip/hip_runtime.h>
#include <hip/hip_bf16.h>
#include <math.h>

#define NB 2
#define NC 256
#define NZ 128
#define NHEADS 8
#define HDIM 64
#define HHID 512
#define EPSF 1e-5f
#define TWO_PI_F 6.283185307179586f

__device__ __forceinline__ float gelu_f(float x){
  // jax.nn.gelu approximate=True: 0.5x(1+tanh(sqrt(2/pi)(x+0.044715x^3)))
  const float u = 0.7978845608028654f * (x + 0.044715f * x * x * x);
  const float t = 1.0f - 2.0f / (__expf(2.0f * u) + 1.0f);  // tanh(u)
  return 0.5f * x * (1.0f + t);
}

// ---------------- Kernel 1: per-b latent precompute ----------------
// k = a@Wk + bk ; v0 = a@Wv + bv ; Kq[z,h,i] = sum_{j in head h} Wq[i,j]*k[z,j]
// bqk[z,h] = sum_{j in head h} bq[j]*k[z,j]
__global__ __launch_bounds__(256) void eca_prep(
    const float* __restrict__ a, const float* __restrict__ Wk, const float* __restrict__ bk,
    const float* __restrict__ Wv, const float* __restrict__ bv,
    const float* __restrict__ Wq, const float* __restrict__ bq,
    float* __restrict__ v0g, float* __restrict__ Kqg, float* __restrict__ bqkg)
{
  const int bz = blockIdx.x;            // b*NZ + z
  const int tid = threadIdx.x;
  __shared__ float s_a[64];
  __shared__ float s_k[512];
  if (tid < 64) s_a[tid] = a[bz * 64 + tid];
  __syncthreads();
  #pragma unroll
  for (int jo = 0; jo < 2; ++jo){
    const int j = tid + jo * 256;
    float accK = bk[j], accV = bv[j];
    for (int i = 0; i < 64; ++i){
      const float av = s_a[i];
      accK += av * Wk[i * 512 + j];
      accV += av * Wv[i * 512 + j];
    }
    s_k[j] = accK;
    v0g[(size_t)bz * 512 + j] = accV;
  }
  __syncthreads();
  #pragma unroll
  for (int io = 0; io < 2; ++io){
    const int idx = tid + io * 256;     // idx = h*64 + i
    const int h = idx >> 6, i = idx & 63;
    float acc = 0.f;
    for (int j = 0; j < 64; ++j)
      acc += Wq[i * 512 + h * 64 + j] * s_k[h * 64 + j];
    Kqg[(size_t)bz * 512 + idx] = acc;
  }
  if (tid < 8){
    float acc = 0.f;
    for (int j = 0; j < 64; ++j) acc += bq[tid * 64 + j] * s_k[tid * 64 + j];
    bqkg[bz * 8 + tid] = acc;
  }
}

// ---------------- Kernel 2: fully fused per-(b,c) ----------------
__global__ __launch_bounds__(256, 2) void eca_fused(
    const float* __restrict__ inputs, const float* __restrict__ p,
    const float* __restrict__ Bq, const float* __restrict__ Wqe, const float* __restrict__ bqe,
    const float* __restrict__ Bv, const float* __restrict__ Wve, const float* __restrict__ bve,
    const float* __restrict__ vW1, const float* __restrict__ vb1,
    const float* __restrict__ vg, const float* __restrict__ vbn,
    const float* __restrict__ vW2, const float* __restrict__ vb2,
    const float* __restrict__ mW1, const float* __restrict__ mb1,
    const float* __restrict__ mg, const float* __restrict__ mbn,
    const float* __restrict__ mW2, const float* __restrict__ mb2,
    const float* __restrict__ Wo, const float* __restrict__ bo,
    const float* __restrict__ v0g, const float* __restrict__ Kqg, const float* __restrict__ bqkg,
    float* __restrict__ out)
{
  const int bc = blockIdx.x;
  const int b = bc >> 8;                // NC = 256
  const int c = bc & 255;
  const int tid = threadIdx.x;

  __shared__ float s_att[NHEADS][NZ];   // logits, then att weights
  __shared__ float s_vfilm[16][HHID];   // film'd values, reused for h2n
  __shared__ float s_embv[16][65];      // padded: rows hit distinct banks
  __shared__ float s_hn[16][65];
  __shared__ float s_f[16][65];
  __shared__ float s_yp[4][HHID];
  __shared__ float s_y[HHID];
  __shared__ float s_qpt[3];

  if (tid < 3) s_qpt[tid] = inputs[(b * NC + c) * 3 + tid];
  __syncthreads();

  // ---------- pass 1: attention logits (2 threads per z) ----------
  {
    const int z = tid >> 1;
    const int half = tid & 1;
    const float iv0 = s_qpt[0] - p[(b * NZ + z) * 3 + 0];
    const float iv1 = s_qpt[1] - p[(b * NZ + z) * 3 + 1];
    const float iv2 = s_qpt[2] - p[(b * NZ + z) * 3 + 2];
    float sn[16], cs[16];
    #pragma unroll
    for (int m = 0; m < 16; ++m){
      const int mm = half * 16 + m;
      const float pr = TWO_PI_F * (iv0 * Bq[mm] + iv1 * Bq[32 + mm] + iv2 * Bq[64 + mm]);
      sincosf(pr, &sn[m], &cs[m]);
    }
    float lg[4] = {0.f, 0.f, 0.f, 0.f};
    const float* KqB = Kqg + ((size_t)(b * NZ + z) * NHEADS + half * 4) * HDIM;
    for (int i4 = 0; i4 < 16; ++i4){
      float e[4];
      #pragma unroll
      for (int ii = 0; ii < 4; ++ii){
        const int i = i4 * 4 + ii;
        float acc = 0.f;
        #pragma unroll
        for (int m = 0; m < 16; ++m){
          const int mm = half * 16 + m;
          acc += sn[m] * Wqe[mm * 64 + i] + cs[m] * Wqe[(mm + 32) * 64 + i];
        }
        acc += __shfl_xor(acc, 1);      // combine the two halves of the RFF sum
        e[ii] = acc + bqe[i];
      }
      #pragma unroll
      for (int h = 0; h < 4; ++h){
        const float4 kq = *(const float4*)(KqB + h * HDIM + i4 * 4);
        lg[h] += e[0] * kq.x + e[1] * kq.y + e[2] * kq.z + e[3] * kq.w;
      }
    }
    #pragma unroll
    for (int h = 0; h < 4; ++h){
      const float bqkv = bqkg[(b * NZ + z) * NHEADS + half * 4 + h];
      s_att[half * 4 + h][z] = (lg[h] + bqkv) * 0.125f;
    }
  }
  __syncthreads();

  // ---------- softmax over z (per head; wave w handles heads 2w,2w+1) ----------
  {
    const int wv = tid >> 6, l = tid & 63;
    #pragma unroll
    for (int hh = 0; hh < 2; ++hh){
      const int h = wv * 2 + hh;
      const float x0 = s_att[h][l], x1 = s_att[h][l + 64];
      float mx = fmaxf(x0, x1);
      #pragma unroll
      for (int off = 32; off; off >>= 1) mx = fmaxf(mx, __shfl_xor(mx, off));
      const float e0 = __expf(x0 - mx), e1 = __expf(x1 - mx);
      float sm = e0 + e1;
      #pragma unroll
      for (int off = 32; off; off >>= 1) sm += __shfl_xor(sm, off);
      const float inv = 1.f / sm;
      s_att[h][l] = e0 * inv;
      s_att[h][l + 64] = e1 * inv;
    }
  }
  __syncthreads();

  // ---------- pass 2: value path, chunked by 16 z ----------
  const int wv = tid >> 6, l = tid & 63;   // GEMM roles: wave owns 4 z-rows, lane owns 8 cols
  const int zl = tid >> 4, s = tid & 15;   // stage roles: 16 threads per z
  const int j0 = l * 8;
  const int hatt = l >> 3;                 // head of this lane's column block
  float mb1r[8], mgr[8], mbnr[8], mb2r[8];
  #pragma unroll
  for (int jj = 0; jj < 8; ++jj){
    mb1r[jj] = mb1[j0 + jj]; mgr[jj] = mg[j0 + jj];
    mbnr[jj] = mbn[j0 + jj]; mb2r[jj] = mb2[j0 + jj];
  }
  float yp[8];
  #pragma unroll
  for (int jj = 0; jj < 8; ++jj) yp[jj] = 0.f;

  for (int ch = 0; ch < 8; ++ch){
    const int z0 = ch * 16;
    // (a) RFF features for v-embedding
    {
      const int z = z0 + zl;
      const float iv0 = s_qpt[0] - p[(b * NZ + z) * 3 + 0];
      const float iv1 = s_qpt[1] - p[(b * NZ + z) * 3 + 1];
      const float iv2 = s_qpt[2] - p[(b * NZ + z) * 3 + 2];
      #pragma unroll
      for (int mq = 0; mq < 2; ++mq){
        const int m = s * 2 + mq;
        const float pr = TWO_PI_F * (iv0 * Bv[m] + iv1 * Bv[32 + m] + iv2 * Bv[64 + m]);
        float s_, c_;
        sincosf(pr, &s_, &c_);
        s_f[zl][m] = s_;
        s_f[zl][m + 32] = c_;
      }
    }
    __syncthreads();
    // (b) emb_v = f @ Wve + bve
    #pragma unroll
    for (int w4 = 0; w4 < 4; ++w4){
      const int i = s + 16 * w4;
      float acc = bve[i];
      for (int m = 0; m < 64; ++m) acc += s_f[zl][m] * Wve[m * 64 + i];
      s_embv[zl][i] = acc;
    }
    __syncthreads();
    // h1 = gelu(emb_v @ vW1 + vb1); LayerNorm64 -> s_hn
    float h1[4];
    #pragma unroll
    for (int w4 = 0; w4 < 4; ++w4){
      const int i = s + 16 * w4;
      float acc = vb1[i];
      for (int m = 0; m < 64; ++m) acc += s_embv[zl][m] * vW1[m * 64 + i];
      h1[w4] = gelu_f(acc);
    }
    float ls = h1[0] + h1[1] + h1[2] + h1[3];
    #pragma unroll
    for (int off = 8; off; off >>= 1) ls += __shfl_xor(ls, off, 16);
    const float mean1 = ls * (1.f / 64.f);
    float lv = 0.f;
    #pragma unroll
    for (int w4 = 0; w4 < 4; ++w4){ const float d = h1[w4] - mean1; lv += d * d; }
    #pragma unroll
    for (int off = 8; off; off >>= 1) lv += __shfl_xor(lv, off, 16);
    const float rs1 = rsqrtf(lv * (1.f / 64.f) + EPSF);
    #pragma unroll
    for (int w4 = 0; w4 < 4; ++w4){
      const int i = s + 16 * w4;
      s_hn[zl][i] = (h1[w4] - mean1) * rs1 * vg[i] + vbn[i];
    }
    __syncthreads();
    // gamma/beta (hn @ vW2 + vb2) + FiLM -> s_vfilm
    {
      const float4* vW2v = (const float4*)vW2;     // row stride 256 float4
      const float4* vb2v = (const float4*)vb2;
      const float4* v0v  = (const float4*)(v0g + ((size_t)(b * NZ) + z0 + zl) * HHID);
      #pragma unroll
      for (int q = 0; q < 8; ++q){
        const int jj4 = (q + s) & 7;               // rotate to spread LDS banks
        const int j4 = s * 8 + jj4;                // float4 col index in [0,128)
        float4 g = vb2v[j4];
        float4 be = vb2v[128 + j4];
        for (int m = 0; m < 64; ++m){
          const float hm = s_hn[zl][m];
          const float4 wg = vW2v[m * 256 + j4];
          const float4 wb = vW2v[m * 256 + 128 + j4];
          g.x += hm * wg.x; g.y += hm * wg.y; g.z += hm * wg.z; g.w += hm * wg.w;
          be.x += hm * wb.x; be.y += hm * wb.y; be.z += hm * wb.z; be.w += hm * wb.w;
        }
        const float4 vv = v0v[j4];
        float4 vf;
        vf.x = vv.x * (1.f + g.x) + be.x;
        vf.y = vv.y * (1.f + g.y) + be.y;
        vf.z = vv.z * (1.f + g.z) + be.z;
        vf.w = vv.w * (1.f + g.w) + be.w;
        *(float4*)&s_vfilm[zl][j4 * 4] = vf;
      }
    }
    __syncthreads();
    // (c) GEMM1: h2 = vfilm @ mW1 (+mb1, gelu, LN512), wave owns rows 4wv..4wv+3
    float acc1[4][8];
    #pragma unroll
    for (int r = 0; r < 4; ++r)
      #pragma unroll
      for (int jj = 0; jj < 8; ++jj) acc1[r][jj] = 0.f;
    {
      const float* Wb = mW1 + j0;
      for (int k = 0; k < 512; k += 4){
        float4 vf[4];
        #pragma unroll
        for (int r = 0; r < 4; ++r) vf[r] = *(const float4*)&s_vfilm[4 * wv + r][k];
        #pragma unroll
        for (int kk = 0; kk < 4; ++kk){
          const float4 wA = *(const float4*)(Wb + (size_t)(k + kk) * 512);
          const float4 wB = *(const float4*)(Wb + (size_t)(k + kk) * 512 + 4);
          #pragma unroll
          for (int r = 0; r < 4; ++r){
            const float v = (kk == 0) ? vf[r].x : ((kk == 1) ? vf[r].y : ((kk == 2) ? vf[r].z : vf[r].w));
            acc1[r][0] += v * wA.x; acc1[r][1] += v * wA.y; acc1[r][2] += v * wA.z; acc1[r][3] += v * wA.w;
            acc1[r][4] += v * wB.x; acc1[r][5] += v * wB.y; acc1[r][6] += v * wB.z; acc1[r][7] += v * wB.w;
          }
        }
      }
    }
    __syncthreads();
    // gelu + LN512, write h2n back into s_vfilm (wave-local rows)
    #pragma unroll
    for (int r = 0; r < 4; ++r){
      float h2[8];
      #pragma unroll
      for (int jj = 0; jj < 8; ++jj) h2[jj] = gelu_f(acc1[r][jj] + mb1r[jj]);
      float lsum = 0.f;
      #pragma unroll
      for (int jj = 0; jj < 8; ++jj) lsum += h2[jj];
      #pragma unroll
      for (int off = 32; off; off >>= 1) lsum += __shfl_xor(lsum, off);
      const float mu = lsum * (1.f / 512.f);
      float lvv = 0.f;
      #pragma unroll
      for (int jj = 0; jj < 8; ++jj){ const float d = h2[jj] - mu; lvv += d * d; }
      #pragma unroll
      for (int off = 32; off; off >>= 1) lvv += __shfl_xor(lvv, off);
      const float rs = rsqrtf(lvv * (1.f / 512.f) + EPSF);
      float4 o0, o1;
      o0.x = (h2[0] - mu) * rs * mgr[0] + mbnr[0];
      o0.y = (h2[1] - mu) * rs * mgr[1] + mbnr[1];
      o0.z = (h2[2] - mu) * rs * mgr[2] + mbnr[2];
      o0.w = (h2[3] - mu) * rs * mgr[3] + mbnr[3];
      o1.x = (h2[4] - mu) * rs * mgr[4] + mbnr[4];
      o1.y = (h2[5] - mu) * rs * mgr[5] + mbnr[5];
      o1.z = (h2[6] - mu) * rs * mgr[6] + mbnr[6];
      o1.w = (h2[7] - mu) * rs * mgr[7] + mbnr[7];
      *(float4*)&s_vfilm[4 * wv + r][j0] = o0;
      *(float4*)&s_vfilm[4 * wv + r][j0 + 4] = o1;
    }
    __syncthreads();
    // GEMM2: vfin = h2n @ mW2 + mb2; accumulate y += att * vfin
    float acc2[4][8];
    #pragma unroll
    for (int r = 0; r < 4; ++r)
      #pragma unroll
      for (int jj = 0; jj < 8; ++jj) acc2[r][jj] = 0.f;
    {
      const float* Wb = mW2 + j0;
      for (int k = 0; k < 512; k += 4){
        float4 vf[4];
        #pragma unroll
        for (int r = 0; r < 4; ++r) vf[r] = *(const float4*)&s_vfilm[4 * wv + r][k];
        #pragma unroll
        for (int kk = 0; kk < 4; ++kk){
          const float4 wA = *(const float4*)(Wb + (size_t)(k + kk) * 512);
          const float4 wB = *(const float4*)(Wb + (size_t)(k + kk) * 512 + 4);
          #pragma unroll
          for (int r = 0; r < 4; ++r){
            const float v = (kk == 0) ? vf[r].x : ((kk == 1) ? vf[r].y : ((kk == 2) ? vf[r].z : vf[r].w));
            acc2[r][0] += v * wA.x; acc2[r][1] += v * wA.y; acc2[r][2] += v * wA.z; acc2[r][3] += v * wA.w;
            acc2[r][4] += v * wB.x; acc2[r][5] += v * wB.y; acc2[r][6] += v * wB.z; acc2[r][7] += v * wB.w;
          }
        }
      }
    }
    #pragma unroll
    for (int r = 0; r < 4; ++r){
      const int z = z0 + 4 * wv + r;
      const float aw = s_att[hatt][z];
      #pragma unroll
      for (int jj = 0; jj < 8; ++jj) yp[jj] += aw * (acc2[r][jj] + mb2r[jj]);
    }
    __syncthreads();
  }

  // ---------- reduce y over waves, final projection ----------
  {
    float4 y0, y1;
    y0.x = yp[0]; y0.y = yp[1]; y0.z = yp[2]; y0.w = yp[3];
    y1.x = yp[4]; y1.y = yp[5]; y1.z = yp[6]; y1.w = yp[7];
    *(float4*)&s_yp[wv][j0] = y0;
    *(float4*)&s_yp[wv][j0 + 4] = y1;
  }
  __syncthreads();
  for (int j = tid; j < HHID; j += 256)
    s_y[j] = s_yp[0][j] + s_yp[1][j] + s_yp[2][j] + s_yp[3][j];
  __syncthreads();
  for (int j = tid; j < HHID; j += 256){
    float acc = bo[j];
    for (int i = 0; i < HHID; i += 4){
      const float4 yv = *(const float4*)&s_y[i];
      acc += yv.x * Wo[(size_t)i * 512 + j] + yv.y * Wo[(size_t)(i + 1) * 512 + j]
           + yv.z * Wo[(size_t)(i + 2) * 512 + j] + yv.w * Wo[(size_t)(i + 3) * 512 + j];
    }
    out[((size_t)(b * NC) + c) * HHID + j] = acc;
  }
}

extern "C" void kernel_launch(void* const* d_in, const int* in_sizes, int n_in,
                              void* d_out, int out_size, void* d_ws, size_t ws_size,
                              hipStream_t stream)
{
  const float* inputs = (const float*)d_in[0];
  const float* p   = (const float*)d_in[1];
  const float* a   = (const float*)d_in[2];
  const float* Bq  = (const float*)d_in[3];
  const float* Wqe = (const float*)d_in[4];
  const float* bqe = (const float*)d_in[5];
  const float* Bv  = (const float*)d_in[6];
  const float* Wve = (const float*)d_in[7];
  const float* bve = (const float*)d_in[8];
  const float* Wq  = (const float*)d_in[9];
  const float* bq  = (const float*)d_in[10];
  const float* Wk  = (const float*)d_in[11];
  const float* bk  = (const float*)d_in[12];
  const float* Wv  = (const float*)d_in[13];
  const float* bv  = (const float*)d_in[14];
  const float* vW1 = (const float*)d_in[15];
  const float* vb1 = (const float*)d_in[16];
  const float* vg  = (const float*)d_in[17];
  const float* vbn = (const float*)d_in[18];
  const float* vW2 = (const float*)d_in[19];
  const float* vb2 = (const float*)d_in[20];
  const float* mW1 = (const float*)d_in[21];
  const float* mb1 = (const float*)d_in[22];
  const float* mg  = (const float*)d_in[23];
  const float* mbn = (const float*)d_in[24];
  const float* mW2 = (const float*)d_in[25];
  const float* mb2 = (const float*)d_in[26];
  const float* Wo  = (const float*)d_in[27];
  const float* bo  = (const float*)d_in[28];
  (void)in_sizes; (void)n_in; (void)out_size; (void)ws_size;

  float* v0g  = (float*)d_ws;                                // [B,Z,512]
  float* Kqg  = v0g + (size_t)NB * NZ * HHID;                // [B,Z,8,64]
  float* bqkg = Kqg + (size_t)NB * NZ * NHEADS * HDIM;       // [B,Z,8]
  float* out  = (float*)d_out;

  eca_prep<<<dim3(NB * NZ), dim3(256), 0, stream>>>(a, Wk, bk, Wv, bv, Wq, bq, v0g, Kqg, bqkg);
  eca_fused<<<dim3(NB * NC), dim3(256), 0, stream>>>(
      inputs, p, Bq, Wqe, bqe, Bv, Wve, bve, vW1, vb1, vg, vbn, vW2, vb2,
      mW1, mb1, mg, mbn, mW2, mb2, Wo, bo, v0g, Kqg, bqkg, out);
}

// Round 2
// 503.405 us; speedup vs baseline: 13.6220x; 13.6220x over previous
//
#include <hip/hip_runtime.h>
#include <hip/hip_bf16.h>
#include <math.h>

#define NB 2
#define NC 256
#define NZ 128
#define NHEADS 8
#define HDIM 64
#define HHID 512
#define EPSF 1e-5f
#define TWO_PI_F 6.283185307179586f

typedef __attribute__((ext_vector_type(8))) short bf16x8;
typedef __attribute__((ext_vector_type(4))) float f32x4;
typedef unsigned short ushort_t;

__device__ __forceinline__ float gelu_f(float x){
  const float u = 0.7978845608028654f * (x + 0.044715f * x * x * x);
  const float t = 1.0f - 2.0f / (__expf(2.0f * u) + 1.0f);  // tanh(u)
  return 0.5f * x * (1.0f + t);
}

__device__ __forceinline__ ushort_t f2bf(float x){
  unsigned int u = __float_as_uint(x);
  unsigned int r = ((u >> 16) & 1u) + 0x7fffu;   // round-to-nearest-even
  return (ushort_t)((u + r) >> 16);
}

// ---------------- K0: pack weights to bf16 in MFMA-fragment order ----------------
// Fragment order: idx = ((s*TILES + t)*64 + L)*8 + j  holds  W[k = s*32 + 8*(L>>4)+j][n = 16*t + (L&15)]
__global__ __launch_bounds__(256) void eca_pack(
    const float* __restrict__ mW1, const float* __restrict__ mW2, const float* __restrict__ vW2,
    ushort_t* __restrict__ W1p, ushort_t* __restrict__ W2p, ushort_t* __restrict__ vW2p)
{
  const int i = blockIdx.x * 256 + threadIdx.x;
  if (i < 262144){            // 16 steps * 32 tiles * 64 lanes * 8
    const int j = i & 7, L = (i >> 3) & 63, t = (i >> 9) & 31, s = i >> 14;
    const int k = s * 32 + ((L >> 4) << 3) + j;
    const int n = (t << 4) + (L & 15);
    W1p[i] = f2bf(mW1[k * 512 + n]);
    W2p[i] = f2bf(mW2[k * 512 + n]);
  }
  if (i < 65536){             // 2 steps * 64 tiles * 64 lanes * 8
    const int j = i & 7, L = (i >> 3) & 63, t = (i >> 9) & 63, s = i >> 15;
    const int k = s * 32 + ((L >> 4) << 3) + j;
    const int n = (t << 4) + (L & 15);
    vW2p[i] = f2bf(vW2[k * 1024 + n]);
  }
}

// ---------------- K1: per-(b,z) latent precompute (unchanged, validated) ----------------
__global__ __launch_bounds__(256) void eca_prep(
    const float* __restrict__ a, const float* __restrict__ Wk, const float* __restrict__ bk,
    const float* __restrict__ Wv, const float* __restrict__ bv,
    const float* __restrict__ Wq, const float* __restrict__ bq,
    float* __restrict__ v0g, float* __restrict__ Kqg, float* __restrict__ bqkg)
{
  const int bz = blockIdx.x;
  const int tid = threadIdx.x;
  __shared__ float s_a[64];
  __shared__ float s_k[512];
  if (tid < 64) s_a[tid] = a[bz * 64 + tid];
  __syncthreads();
  #pragma unroll
  for (int jo = 0; jo < 2; ++jo){
    const int j = tid + jo * 256;
    float accK = bk[j], accV = bv[j];
    for (int i = 0; i < 64; ++i){
      const float av = s_a[i];
      accK += av * Wk[i * 512 + j];
      accV += av * Wv[i * 512 + j];
    }
    s_k[j] = accK;
    v0g[(size_t)bz * 512 + j] = accV;
  }
  __syncthreads();
  #pragma unroll
  for (int io = 0; io < 2; ++io){
    const int idx = tid + io * 256;
    const int h = idx >> 6, i = idx & 63;
    float acc = 0.f;
    for (int j = 0; j < 64; ++j)
      acc += Wq[i * 512 + h * 64 + j] * s_k[h * 64 + j];
    Kqg[(size_t)bz * 512 + idx] = acc;
  }
  if (tid < 8){
    float acc = 0.f;
    for (int j = 0; j < 64; ++j) acc += bq[tid * 64 + j] * s_k[tid * 64 + j];
    bqkg[bz * 8 + tid] = acc;
  }
}

// GEMM helper: A (bf16, swizzled) in sbw [16 rows x 512 k], B from packed weights staged in s_slab.
__device__ __forceinline__ void gemm_block(f32x4* acc, const ushort_t* __restrict__ Wp,
                                           const char* sbw, ushort_t* s_slab,
                                           const int tid, const int L)
{
  const int al = L & 15, g = L >> 4;
  #pragma unroll
  for (int jh = 0; jh < 2; ++jh){
    for (int s = 0; s < 16; ++s){
      __syncthreads();                                   // previous slab readers done
      const uint4* srcv = (const uint4*)(Wp + (size_t)(s * 32 + jh * 16) * 512);
      uint4* dstv = (uint4*)s_slab;
      dstv[tid] = srcv[tid];
      dstv[tid + 512] = srcv[tid + 512];
      __syncthreads();                                   // slab ready
      const bf16x8 af = *(const bf16x8*)(sbw + al * 1024 + ((s * 64 + g * 16) ^ ((al & 7) << 4)));
      #pragma unroll
      for (int tt = 0; tt < 16; ++tt){
        const bf16x8 bfv = *(const bf16x8*)((const char*)s_slab + (tt * 64 + L) * 16);
        acc[jh * 16 + tt] = __builtin_amdgcn_mfma_f32_16x16x32_bf16(af, bfv, acc[jh * 16 + tt], 0, 0, 0);
      }
    }
  }
}

// ---------------- K3: fused per-(b,c), all 128 z per block, MFMA GEMMs ----------------
__global__ __launch_bounds__(512, 2) void eca_main(
    const float* __restrict__ inputs, const float* __restrict__ p,
    const float* __restrict__ Bq, const float* __restrict__ Wqe, const float* __restrict__ bqe,
    const float* __restrict__ Bv, const float* __restrict__ Wve, const float* __restrict__ bve,
    const float* __restrict__ vW1, const float* __restrict__ vb1,
    const float* __restrict__ vg, const float* __restrict__ vbn,
    const float* __restrict__ vb2,
    const float* __restrict__ mb1, const float* __restrict__ mg, const float* __restrict__ mbn,
    const float* __restrict__ mb2,
    const float* __restrict__ v0g, const float* __restrict__ Kqg, const float* __restrict__ bqkg,
    const ushort_t* __restrict__ W1p, const ushort_t* __restrict__ W2p, const ushort_t* __restrict__ vW2p,
    float* __restrict__ yout)
{
  const int bc = blockIdx.x;
  const int b = bc >> 8;
  const int tid = threadIdx.x;
  const int w = tid >> 6, L = tid & 63;
  const int bz0 = b * NZ;

  __shared__ __align__(16) ushort_t s_big[8][16][512];   // 128 KB: per-wave A buffer (vfilm -> h2n), XOR-swizzled
  __shared__ __align__(16) ushort_t s_slab[8192];        // 16 KB: weight slab / s_hn / y-partials
  __shared__ float s_att[NHEADS][NZ];                    // 4 KB
  __shared__ float s_mb1[512], s_mg[512], s_mbn[512], s_mb2[512];  // 8 KB
  __shared__ float s_qpt[3];

  for (int i = tid; i < 512; i += 512){ s_mb1[i]=mb1[i]; s_mg[i]=mg[i]; s_mbn[i]=mbn[i]; s_mb2[i]=mb2[i]; }
  if (tid < 3) s_qpt[tid] = inputs[bc * 3 + tid];
  __syncthreads();

  // ---------- pass 1: attention logits (threads 0..255; 2 threads per z) ----------
  if (tid < 256){
    const int z = tid >> 1;
    const int half = tid & 1;
    const float iv0 = s_qpt[0] - p[(bz0 + z) * 3 + 0];
    const float iv1 = s_qpt[1] - p[(bz0 + z) * 3 + 1];
    const float iv2 = s_qpt[2] - p[(bz0 + z) * 3 + 2];
    float sn[16], cs[16];
    #pragma unroll
    for (int m = 0; m < 16; ++m){
      const int mm = half * 16 + m;
      const float pr = TWO_PI_F * (iv0 * Bq[mm] + iv1 * Bq[32 + mm] + iv2 * Bq[64 + mm]);
      sincosf(pr, &sn[m], &cs[m]);
    }
    float lg[4] = {0.f, 0.f, 0.f, 0.f};
    const float* KqB = Kqg + ((size_t)(bz0 + z) * NHEADS + half * 4) * HDIM;
    for (int i4 = 0; i4 < 16; ++i4){
      float e[4];
      #pragma unroll
      for (int ii = 0; ii < 4; ++ii){
        const int i = i4 * 4 + ii;
        float acc = 0.f;
        #pragma unroll
        for (int m = 0; m < 16; ++m){
          const int mm = half * 16 + m;
          acc += sn[m] * Wqe[mm * 64 + i] + cs[m] * Wqe[(mm + 32) * 64 + i];
        }
        acc += __shfl_xor(acc, 1);
        e[ii] = acc + bqe[i];
      }
      #pragma unroll
      for (int h = 0; h < 4; ++h){
        const float4 kq = *(const float4*)(KqB + h * HDIM + i4 * 4);
        lg[h] += e[0] * kq.x + e[1] * kq.y + e[2] * kq.z + e[3] * kq.w;
      }
    }
    #pragma unroll
    for (int h = 0; h < 4; ++h){
      const float bqkv = bqkg[(bz0 + z) * NHEADS + half * 4 + h];
      s_att[half * 4 + h][z] = (lg[h] + bqkv) * 0.125f;
    }
  }
  __syncthreads();

  // ---------- softmax over z: wave w handles head w ----------
  {
    const float x0 = s_att[w][L], x1 = s_att[w][L + 64];
    float mx = fmaxf(x0, x1);
    #pragma unroll
    for (int off = 32; off; off >>= 1) mx = fmaxf(mx, __shfl_xor(mx, off));
    const float e0 = __expf(x0 - mx), e1 = __expf(x1 - mx);
    float sm = e0 + e1;
    #pragma unroll
    for (int off = 32; off; off >>= 1) sm += __shfl_xor(sm, off);
    const float inv = 1.f / sm;
    s_att[w][L] = e0 * inv;
    s_att[w][L + 64] = e1 * inv;
  }
  __syncthreads();

  // ---------- front (f32): RFF f -> embv -> h1 -> LN64 -> hn (bf16 into s_slab) ----------
  {
    const int rloc = L >> 2, q = L & 3;                   // wave w owns z rows w*16 .. w*16+15
    const int zz = w * 16 + rloc;
    float* s_fw = (float*)((char*)s_big + w * 16384);     // [16][64] RFF features
    float* s_ew = s_fw + 1024;                            // [16][64] embv
    const float iv0 = s_qpt[0] - p[(bz0 + zz) * 3 + 0];
    const float iv1 = s_qpt[1] - p[(bz0 + zz) * 3 + 1];
    const float iv2 = s_qpt[2] - p[(bz0 + zz) * 3 + 2];
    #pragma unroll
    for (int mi = 0; mi < 8; ++mi){
      const int m = q * 8 + mi;
      const float pr = TWO_PI_F * (iv0 * Bv[m] + iv1 * Bv[32 + m] + iv2 * Bv[64 + m]);
      float sn, cn; sincosf(pr, &sn, &cn);
      s_fw[rloc * 64 + m] = sn;
      s_fw[rloc * 64 + 32 + m] = cn;
    }
    __syncthreads();
    float e[16];
    #pragma unroll
    for (int ii = 0; ii < 16; ++ii) e[ii] = bve[q * 16 + ii];
    for (int ph = 0; ph < 64; ++ph){
      const float fv = s_fw[rloc * 64 + ph];
      const float4* wr = (const float4*)(Wve + ph * 64 + q * 16);
      float wvv[16];
      *(float4*)&wvv[0] = wr[0]; *(float4*)&wvv[4] = wr[1];
      *(float4*)&wvv[8] = wr[2]; *(float4*)&wvv[12] = wr[3];
      #pragma unroll
      for (int ii = 0; ii < 16; ++ii) e[ii] += fv * wvv[ii];
    }
    __syncthreads();
    #pragma unroll
    for (int ii = 0; ii < 16; ++ii) s_ew[rloc * 64 + q * 16 + ii] = e[ii];
    __syncthreads();
    float h[16];
    #pragma unroll
    for (int ii = 0; ii < 16; ++ii) h[ii] = vb1[q * 16 + ii];
    for (int ph = 0; ph < 64; ++ph){
      const float fv = s_ew[rloc * 64 + ph];
      const float4* wr = (const float4*)(vW1 + ph * 64 + q * 16);
      float wvv[16];
      *(float4*)&wvv[0] = wr[0]; *(float4*)&wvv[4] = wr[1];
      *(float4*)&wvv[8] = wr[2]; *(float4*)&wvv[12] = wr[3];
      #pragma unroll
      for (int ii = 0; ii < 16; ++ii) h[ii] += fv * wvv[ii];
    }
    #pragma unroll
    for (int ii = 0; ii < 16; ++ii) h[ii] = gelu_f(h[ii]);
    float ls = 0.f;
    #pragma unroll
    for (int ii = 0; ii < 16; ++ii) ls += h[ii];
    ls += __shfl_xor(ls, 1); ls += __shfl_xor(ls, 2);
    const float mu = ls * (1.f / 64.f);
    float lv = 0.f;
    #pragma unroll
    for (int ii = 0; ii < 16; ++ii){ const float d = h[ii] - mu; lv += d * d; }
    lv += __shfl_xor(lv, 1); lv += __shfl_xor(lv, 2);
    const float rs = rsqrtf(lv * (1.f / 64.f) + EPSF);
    ushort_t* s_hn = (ushort_t*)s_slab;                   // [8][16][64] bf16
    #pragma unroll
    for (int ii = 0; ii < 16; ++ii){
      const int i = q * 16 + ii;
      s_hn[(w * 16 + rloc) * 64 + i] = f2bf((h[ii] - mu) * rs * vg[i] + vbn[i]);
    }
  }
  __syncthreads();

  // ---------- gb MFMA: [16 z x 64] @ vW2 [64 x 1024] -> FiLM -> vfilm (bf16, swizzled s_big) ----------
  {
    const ushort_t* s_hn = (const ushort_t*)s_slab;
    const int al = L & 15, g = L >> 4;
    const bf16x8 a0 = *(const bf16x8*)(s_hn + (w * 16 + al) * 64 + g * 8);
    const bf16x8 a1 = *(const bf16x8*)(s_hn + (w * 16 + al) * 64 + 32 + g * 8);
    char* sbw = (char*)s_big + w * 16384;
    for (int t = 0; t < 32; ++t){
      const bf16x8 bg0 = *(const bf16x8*)(vW2p + (size_t)((0 * 64 + t) * 64 + L) * 8);
      const bf16x8 bg1 = *(const bf16x8*)(vW2p + (size_t)((1 * 64 + t) * 64 + L) * 8);
      const bf16x8 bb0 = *(const bf16x8*)(vW2p + (size_t)((0 * 64 + t + 32) * 64 + L) * 8);
      const bf16x8 bb1 = *(const bf16x8*)(vW2p + (size_t)((1 * 64 + t + 32) * 64 + L) * 8);
      f32x4 ag = {0.f,0.f,0.f,0.f}, ab = {0.f,0.f,0.f,0.f};
      ag = __builtin_amdgcn_mfma_f32_16x16x32_bf16(a0, bg0, ag, 0, 0, 0);
      ag = __builtin_amdgcn_mfma_f32_16x16x32_bf16(a1, bg1, ag, 0, 0, 0);
      ab = __builtin_amdgcn_mfma_f32_16x16x32_bf16(a0, bb0, ab, 0, 0, 0);
      ab = __builtin_amdgcn_mfma_f32_16x16x32_bf16(a1, bb1, ab, 0, 0, 0);
      const int n = t * 16 + al;
      const float gbias = vb2[n], bbias = vb2[512 + n];
      #pragma unroll
      for (int r = 0; r < 4; ++r){
        const int row = g * 4 + r;
        const float v0v = v0g[(size_t)(bz0 + w * 16 + row) * 512 + n];
        const float vf = v0v * (1.f + ag[r] + gbias) + (ab[r] + bbias);
        *(ushort_t*)(sbw + row * 1024 + ((n * 2) ^ ((row & 7) << 4))) = f2bf(vf);
      }
    }
  }
  __syncthreads();

  // ---------- GEMM1: h2 = vfilm @ mW1 ; gelu + LN512 -> h2n (back into s_big) ----------
  f32x4 acc[32];
  #pragma unroll
  for (int i = 0; i < 32; ++i) acc[i] = (f32x4){0.f,0.f,0.f,0.f};
  {
    const char* sbw = (const char*)s_big + w * 16384;
    gemm_block(acc, W1p, sbw, s_slab, tid, L);
  }
  {
    const int al = L & 15, g = L >> 4;
    float mu[4], rs[4];
    float rsum[4] = {0.f,0.f,0.f,0.f};
    #pragma unroll
    for (int t = 0; t < 32; ++t){
      const float bb = s_mb1[t * 16 + al];
      #pragma unroll
      for (int r = 0; r < 4; ++r){
        const float v = gelu_f(acc[t][r] + bb);
        acc[t][r] = v; rsum[r] += v;
      }
    }
    #pragma unroll
    for (int r = 0; r < 4; ++r){
      float x = rsum[r];
      x += __shfl_xor(x, 1); x += __shfl_xor(x, 2); x += __shfl_xor(x, 4); x += __shfl_xor(x, 8);
      mu[r] = x * (1.f / 512.f);
    }
    float rvar[4] = {0.f,0.f,0.f,0.f};
    #pragma unroll
    for (int t = 0; t < 32; ++t)
      #pragma unroll
      for (int r = 0; r < 4; ++r){ const float d = acc[t][r] - mu[r]; rvar[r] += d * d; }
    #pragma unroll
    for (int r = 0; r < 4; ++r){
      float x = rvar[r];
      x += __shfl_xor(x, 1); x += __shfl_xor(x, 2); x += __shfl_xor(x, 4); x += __shfl_xor(x, 8);
      rs[r] = rsqrtf(x * (1.f / 512.f) + EPSF);
    }
    char* sbw = (char*)s_big + w * 16384;
    #pragma unroll
    for (int t = 0; t < 32; ++t){
      const int n = t * 16 + al;
      const float gmm = s_mg[n], bnn = s_mbn[n];
      #pragma unroll
      for (int r = 0; r < 4; ++r){
        const int row = 4 * g + r;
        *(ushort_t*)(sbw + row * 1024 + ((n * 2) ^ ((row & 7) << 4))) =
            f2bf((acc[t][r] - mu[r]) * rs[r] * gmm + bnn);
      }
    }
  }
  __syncthreads();

  // ---------- GEMM2: vfin = h2n @ mW2 + mb2 ; y += att * vfin ----------
  #pragma unroll
  for (int i = 0; i < 32; ++i) acc[i] = (f32x4){0.f,0.f,0.f,0.f};
  {
    const char* sbw = (const char*)s_big + w * 16384;
    gemm_block(acc, W2p, sbw, s_slab, tid, L);
  }
  {
    const int al = L & 15, g = L >> 4;
    __syncthreads();                                      // all waves done reading slab
    float* s_yp = (float*)s_slab;                         // [8][512]
    #pragma unroll
    for (int t = 0; t < 32; ++t){
      const int n = t * 16 + al;
      const int h = n >> 6;
      const float bb = s_mb2[n];
      float sacc = 0.f;
      #pragma unroll
      for (int r = 0; r < 4; ++r){
        const int zr = w * 16 + 4 * g + r;
        sacc += s_att[h][zr] * (acc[t][r] + bb);
      }
      sacc += __shfl_xor(sacc, 16);
      sacc += __shfl_xor(sacc, 32);
      if (g == 0) s_yp[w * 512 + n] = sacc;
    }
    __syncthreads();
    float ysum = 0.f;
    #pragma unroll
    for (int ww = 0; ww < 8; ++ww) ysum += s_yp[ww * 512 + tid];
    yout[(size_t)bc * 512 + tid] = ysum;
  }
}

// ---------------- K5: out = y @ Wo + bo (f32, Wo read ~16x total) ----------------
__global__ __launch_bounds__(256) void eca_out(
    const float* __restrict__ y, const float* __restrict__ Wo, const float* __restrict__ bo,
    float* __restrict__ out)
{
  const int rt = blockIdx.x >> 2, ct = blockIdx.x & 3;    // 16 row-tiles x 4 col-tiles
  const int tid = threadIdx.x;
  __shared__ float s_y[32][512];
  const float* yb = y + (size_t)rt * 32 * 512;
  for (int i = tid; i < 32 * 128; i += 256)
    ((float4*)&s_y[0][0])[i] = ((const float4*)yb)[i];
  __syncthreads();
  const int jc = ct * 128 + (tid & 31) * 4;
  const int r0 = (tid >> 5) * 4;
  float acc[4][4] = {};
  #pragma unroll 4
  for (int k = 0; k < 512; ++k){
    const float4 wv = *(const float4*)(Wo + (size_t)k * 512 + jc);
    #pragma unroll
    for (int r = 0; r < 4; ++r){
      const float yv = s_y[r0 + r][k];
      acc[r][0] += yv * wv.x; acc[r][1] += yv * wv.y;
      acc[r][2] += yv * wv.z; acc[r][3] += yv * wv.w;
    }
  }
  const float4 bv4 = *(const float4*)(bo + jc);
  #pragma unroll
  for (int r = 0; r < 4; ++r){
    float4 o;
    o.x = acc[r][0] + bv4.x; o.y = acc[r][1] + bv4.y;
    o.z = acc[r][2] + bv4.z; o.w = acc[r][3] + bv4.w;
    *(float4*)(out + (size_t)(rt * 32 + r0 + r) * 512 + jc) = o;
  }
}

extern "C" void kernel_launch(void* const* d_in, const int* in_sizes, int n_in,
                              void* d_out, int out_size, void* d_ws, size_t ws_size,
                              hipStream_t stream)
{
  const float* inputs = (const float*)d_in[0];
  const float* p   = (const float*)d_in[1];
  const float* a   = (const float*)d_in[2];
  const float* Bq  = (const float*)d_in[3];
  const float* Wqe = (const float*)d_in[4];
  const float* bqe = (const float*)d_in[5];
  const float* Bv  = (const float*)d_in[6];
  const float* Wve = (const float*)d_in[7];
  const float* bve = (const float*)d_in[8];
  const float* Wq  = (const float*)d_in[9];
  const float* bq  = (const float*)d_in[10];
  const float* Wk  = (const float*)d_in[11];
  const float* bk  = (const float*)d_in[12];
  const float* Wv  = (const float*)d_in[13];
  const float* bv  = (const float*)d_in[14];
  const float* vW1 = (const float*)d_in[15];
  const float* vb1 = (const float*)d_in[16];
  const float* vg  = (const float*)d_in[17];
  const float* vbn = (const float*)d_in[18];
  const float* vW2 = (const float*)d_in[19];
  const float* vb2 = (const float*)d_in[20];
  const float* mW1 = (const float*)d_in[21];
  const float* mb1 = (const float*)d_in[22];
  const float* mg  = (const float*)d_in[23];
  const float* mbn = (const float*)d_in[24];
  const float* mW2 = (const float*)d_in[25];
  const float* mb2 = (const float*)d_in[26];
  const float* Wo  = (const float*)d_in[27];
  const float* bo  = (const float*)d_in[28];
  (void)in_sizes; (void)n_in; (void)out_size; (void)ws_size;

  float* v0g  = (float*)d_ws;                        // [2*128*512]
  float* Kqg  = v0g + 131072;                        // [2*128*512]
  float* bqkg = Kqg + 131072;                        // [2*128*8] (padded to 2048)
  float* yws  = bqkg + 2048;                         // [512*512]
  ushort_t* W1p  = (ushort_t*)(yws + 262144);        // 262144 bf16
  ushort_t* W2p  = W1p + 262144;                     // 262144 bf16
  ushort_t* vW2p = W2p + 262144;                     // 65536 bf16
  float* out = (float*)d_out;

  eca_pack<<<dim3(1024), dim3(256), 0, stream>>>(mW1, mW2, vW2, W1p, W2p, vW2p);
  eca_prep<<<dim3(NB * NZ), dim3(256), 0, stream>>>(a, Wk, bk, Wv, bv, Wq, bq, v0g, Kqg, bqkg);
  eca_main<<<dim3(NB * NC), dim3(512), 0, stream>>>(
      inputs, p, Bq, Wqe, bqe, Bv, Wve, bve, vW1, vb1, vg, vbn, vb2,
      mb1, mg, mbn, mb2, v0g, Kqg, bqkg, W1p, W2p, vW2p, yws);
  eca_out<<<dim3(64), dim3(256), 0, stream>>>(yws, Wo, bo, out);
}

// Round 3
// 447.961 us; speedup vs baseline: 15.3080x; 1.1238x over previous
//
#include <hip/hip_runtime.h>
#include <hip/hip_bf16.h>
#include <math.h>

#define NB 2
#define NC 256
#define NZ 128
#define NHEADS 8
#define HDIM 64
#define HHID 512
#define EPSF 1e-5f
#define TWO_PI_F 6.283185307179586f

typedef __attribute__((ext_vector_type(8))) short bf16x8;
typedef __attribute__((ext_vector_type(4))) float f32x4;
typedef unsigned short ushort_t;

__device__ __forceinline__ float gelu_f(float x){
  const float u = 0.7978845608028654f * (x + 0.044715f * x * x * x);
  const float t = 1.0f - 2.0f / (__expf(2.0f * u) + 1.0f);  // tanh(u)
  return 0.5f * x * (1.0f + t);
}

__device__ __forceinline__ ushort_t f2bf(float x){
  unsigned int u = __float_as_uint(x);
  unsigned int r = ((u >> 16) & 1u) + 0x7fffu;   // round-to-nearest-even
  return (ushort_t)((u + r) >> 16);
}

// ---------------- K0: pack weights to bf16 in MFMA-fragment order ----------------
// W1p/W2p: idx = ((s*32 + t)*64 + L)*8 + j holds W[k=s*32+8*(L>>4)+j][n=16*t+(L&15)]
// vW2p:   idx = (((s*32+tp)*2+gb)*64 + L)*8 + j holds vW2[k][n=tp*16+(L&15)+gb*512]
__global__ __launch_bounds__(256) void eca_pack(
    const float* __restrict__ mW1, const float* __restrict__ mW2, const float* __restrict__ vW2,
    ushort_t* __restrict__ W1p, ushort_t* __restrict__ W2p, ushort_t* __restrict__ vW2p)
{
  const int i = blockIdx.x * 256 + threadIdx.x;
  if (i < 262144){
    const int j = i & 7, L = (i >> 3) & 63, t = (i >> 9) & 31, s = i >> 14;
    const int k = s * 32 + ((L >> 4) << 3) + j;
    const int n = (t << 4) + (L & 15);
    W1p[i] = f2bf(mW1[k * 512 + n]);
    W2p[i] = f2bf(mW2[k * 512 + n]);
  }
  if (i < 65536){
    const int j = i & 7, L = (i >> 3) & 63, gb = (i >> 9) & 1, tp = (i >> 10) & 31, s = i >> 15;
    const int k = s * 32 + ((L >> 4) << 3) + j;
    const int n = (tp << 4) + (L & 15) + gb * 512;
    vW2p[i] = f2bf(vW2[k * 1024 + n]);
  }
}

// ---------------- K1: per-(b,z) latent precompute (validated) ----------------
__global__ __launch_bounds__(256) void eca_prep(
    const float* __restrict__ a, const float* __restrict__ Wk, const float* __restrict__ bk,
    const float* __restrict__ Wv, const float* __restrict__ bv,
    const float* __restrict__ Wq, const float* __restrict__ bq,
    float* __restrict__ v0g, float* __restrict__ Kqg, float* __restrict__ bqkg)
{
  const int bz = blockIdx.x;
  const int tid = threadIdx.x;
  __shared__ float s_a[64];
  __shared__ float s_k[512];
  if (tid < 64) s_a[tid] = a[bz * 64 + tid];
  __syncthreads();
  #pragma unroll
  for (int jo = 0; jo < 2; ++jo){
    const int j = tid + jo * 256;
    float accK = bk[j], accV = bv[j];
    for (int i = 0; i < 64; ++i){
      const float av = s_a[i];
      accK += av * Wk[i * 512 + j];
      accV += av * Wv[i * 512 + j];
    }
    s_k[j] = accK;
    v0g[(size_t)bz * 512 + j] = accV;
  }
  __syncthreads();
  #pragma unroll
  for (int io = 0; io < 2; ++io){
    const int idx = tid + io * 256;
    const int h = idx >> 6, i = idx & 63;
    float acc = 0.f;
    for (int j = 0; j < 64; ++j)
      acc += Wq[i * 512 + h * 64 + j] * s_k[h * 64 + j];
    Kqg[(size_t)bz * 512 + idx] = acc;
  }
  if (tid < 8){
    float acc = 0.f;
    for (int j = 0; j < 64; ++j) acc += bq[tid * 64 + j] * s_k[tid * 64 + j];
    bqkg[bz * 8 + tid] = acc;
  }
}

// 512x512 GEMM, wave layout (1,8): wave owns all 128 rows x 64 cols (t = w*4..w*4+3).
// A from LDS frag-packed (conflict-free linear reads), B streamed from global (L2) double-buffered.
__device__ __forceinline__ void gemm512(f32x4 (&acc)[8][4], const ushort_t* __restrict__ Wp,
                                        const ushort_t* sA, const int w, const int L)
{
  bf16x8 B0[4], B1[4];
  #pragma unroll
  for (int ct = 0; ct < 4; ++ct)
    B0[ct] = *(const bf16x8*)(Wp + (size_t)((w * 4 + ct) * 64 + L) * 8);
  #pragma unroll
  for (int s2 = 0; s2 < 8; ++s2){
    const int s = 2 * s2;
    #pragma unroll
    for (int ct = 0; ct < 4; ++ct)
      B1[ct] = *(const bf16x8*)(Wp + (size_t)(((s + 1) * 32 + w * 4 + ct) * 64 + L) * 8);
    #pragma unroll
    for (int rt = 0; rt < 8; ++rt){
      const bf16x8 a = *(const bf16x8*)(sA + ((s * 8 + rt) * 64 + L) * 8);
      #pragma unroll
      for (int ct = 0; ct < 4; ++ct)
        acc[rt][ct] = __builtin_amdgcn_mfma_f32_16x16x32_bf16(a, B0[ct], acc[rt][ct], 0, 0, 0);
    }
    if (s2 < 7){
      #pragma unroll
      for (int ct = 0; ct < 4; ++ct)
        B0[ct] = *(const bf16x8*)(Wp + (size_t)(((s + 2) * 32 + w * 4 + ct) * 64 + L) * 8);
    }
    #pragma unroll
    for (int rt = 0; rt < 8; ++rt){
      const bf16x8 a = *(const bf16x8*)(sA + (((s + 1) * 8 + rt) * 64 + L) * 8);
      #pragma unroll
      for (int ct = 0; ct < 4; ++ct)
        acc[rt][ct] = __builtin_amdgcn_mfma_f32_16x16x32_bf16(a, B1[ct], acc[rt][ct], 0, 0, 0);
    }
  }
}

// ---------------- K3: fused per-(b,c) ----------------
__global__ __launch_bounds__(512, 2) void eca_main(
    const float* __restrict__ inputs, const float* __restrict__ p,
    const float* __restrict__ Bq, const float* __restrict__ Wqe, const float* __restrict__ bqe,
    const float* __restrict__ Bv, const float* __restrict__ Wve, const float* __restrict__ bve,
    const float* __restrict__ vW1, const float* __restrict__ vb1,
    const float* __restrict__ vg, const float* __restrict__ vbn,
    const float* __restrict__ vb2,
    const float* __restrict__ mb1, const float* __restrict__ mg, const float* __restrict__ mbn,
    const float* __restrict__ mb2,
    const float* __restrict__ v0g, const float* __restrict__ Kqg, const float* __restrict__ bqkg,
    const ushort_t* __restrict__ W1p, const ushort_t* __restrict__ W2p, const ushort_t* __restrict__ vW2p,
    float* __restrict__ yout)
{
  const int bc = blockIdx.x;
  const int b = bc >> 8;
  const int tid = threadIdx.x;
  const int w = tid >> 6, L = tid & 63;
  const int al = L & 15, g = L >> 4;
  const int bz0 = b * NZ;

  __shared__ __align__(16) ushort_t s_A[16 * 8 * 64 * 8];   // 128KB A-frags [s][rt][L][8]
  __shared__ __align__(16) ushort_t s_hn[2 * 8 * 64 * 8];   // 16KB hn frags
  __shared__ float s_att[NHEADS][NZ];                        // 4KB
  __shared__ float s_ln[128][8][2];                          // 8KB row partials (sum,sumsq)
  __shared__ float s_mu[128], s_rs[128];                     // 1KB
  __shared__ float s_qpt[3];

  if (tid < 3) s_qpt[tid] = inputs[bc * 3 + tid];
  __syncthreads();

  // ---------- pass 1: attention logits (threads 0..255; 2 per z) ----------
  if (tid < 256){
    const int z = tid >> 1;
    const int half = tid & 1;
    const float iv0 = s_qpt[0] - p[(bz0 + z) * 3 + 0];
    const float iv1 = s_qpt[1] - p[(bz0 + z) * 3 + 1];
    const float iv2 = s_qpt[2] - p[(bz0 + z) * 3 + 2];
    float sn[16], cs[16];
    #pragma unroll
    for (int m = 0; m < 16; ++m){
      const int mm = half * 16 + m;
      const float pr = TWO_PI_F * (iv0 * Bq[mm] + iv1 * Bq[32 + mm] + iv2 * Bq[64 + mm]);
      sincosf(pr, &sn[m], &cs[m]);
    }
    float lg[4] = {0.f, 0.f, 0.f, 0.f};
    const float* KqB = Kqg + ((size_t)(bz0 + z) * NHEADS + half * 4) * HDIM;
    for (int i4 = 0; i4 < 16; ++i4){
      float e[4];
      #pragma unroll
      for (int ii = 0; ii < 4; ++ii){
        const int i = i4 * 4 + ii;
        float acc = 0.f;
        #pragma unroll
        for (int m = 0; m < 16; ++m){
          const int mm = half * 16 + m;
          acc += sn[m] * Wqe[mm * 64 + i] + cs[m] * Wqe[(mm + 32) * 64 + i];
        }
        acc += __shfl_xor(acc, 1);
        e[ii] = acc + bqe[i];
      }
      #pragma unroll
      for (int h = 0; h < 4; ++h){
        const float4 kq = *(const float4*)(KqB + h * HDIM + i4 * 4);
        lg[h] += e[0] * kq.x + e[1] * kq.y + e[2] * kq.z + e[3] * kq.w;
      }
    }
    #pragma unroll
    for (int h = 0; h < 4; ++h){
      const float bqkv = bqkg[(bz0 + z) * NHEADS + half * 4 + h];
      s_att[half * 4 + h][z] = (lg[h] + bqkv) * 0.125f;
    }
  }
  __syncthreads();

  // ---------- softmax over z: wave w handles head w (wave-local row) ----------
  {
    const float x0 = s_att[w][L], x1 = s_att[w][L + 64];
    float mx = fmaxf(x0, x1);
    #pragma unroll
    for (int off = 32; off; off >>= 1) mx = fmaxf(mx, __shfl_xor(mx, off));
    const float e0 = __expf(x0 - mx), e1 = __expf(x1 - mx);
    float sm = e0 + e1;
    #pragma unroll
    for (int off = 32; off; off >>= 1) sm += __shfl_xor(sm, off);
    const float inv = 1.f / sm;
    s_att[w][L] = e0 * inv;
    s_att[w][L + 64] = e1 * inv;
  }

  // ---------- front (f32): RFF f -> embv -> h1 -> LN64 -> hn (bf16 frag-packed) ----------
  {
    const int rloc = L >> 2, q = L & 3;                   // wave w owns z rows w*16..w*16+15
    const int zz = w * 16 + rloc;
    float* s_fw = (float*)s_A + w * 2048;                 // [16][64] RFF features
    float* s_ew = s_fw + 1024;                            // [16][64] embv
    const float iv0 = s_qpt[0] - p[(bz0 + zz) * 3 + 0];
    const float iv1 = s_qpt[1] - p[(bz0 + zz) * 3 + 1];
    const float iv2 = s_qpt[2] - p[(bz0 + zz) * 3 + 2];
    #pragma unroll
    for (int mi = 0; mi < 8; ++mi){
      const int m = q * 8 + mi;
      const float pr = TWO_PI_F * (iv0 * Bv[m] + iv1 * Bv[32 + m] + iv2 * Bv[64 + m]);
      float sn, cn; sincosf(pr, &sn, &cn);
      s_fw[rloc * 64 + m] = sn;
      s_fw[rloc * 64 + 32 + m] = cn;
    }
    __syncthreads();
    float e[16];
    #pragma unroll
    for (int ii = 0; ii < 16; ++ii) e[ii] = bve[q * 16 + ii];
    #pragma unroll 4
    for (int ph = 0; ph < 64; ++ph){
      const float fv = s_fw[rloc * 64 + ph];
      const float4* wr = (const float4*)(Wve + ph * 64 + q * 16);
      float wvv[16];
      *(float4*)&wvv[0] = wr[0]; *(float4*)&wvv[4] = wr[1];
      *(float4*)&wvv[8] = wr[2]; *(float4*)&wvv[12] = wr[3];
      #pragma unroll
      for (int ii = 0; ii < 16; ++ii) e[ii] += fv * wvv[ii];
    }
    __syncthreads();
    #pragma unroll
    for (int ii = 0; ii < 16; ++ii) s_ew[rloc * 64 + q * 16 + ii] = e[ii];
    __syncthreads();
    float h[16];
    #pragma unroll
    for (int ii = 0; ii < 16; ++ii) h[ii] = vb1[q * 16 + ii];
    #pragma unroll 4
    for (int ph = 0; ph < 64; ++ph){
      const float fv = s_ew[rloc * 64 + ph];
      const float4* wr = (const float4*)(vW1 + ph * 64 + q * 16);
      float wvv[16];
      *(float4*)&wvv[0] = wr[0]; *(float4*)&wvv[4] = wr[1];
      *(float4*)&wvv[8] = wr[2]; *(float4*)&wvv[12] = wr[3];
      #pragma unroll
      for (int ii = 0; ii < 16; ++ii) h[ii] += fv * wvv[ii];
    }
    #pragma unroll
    for (int ii = 0; ii < 16; ++ii) h[ii] = gelu_f(h[ii]);
    float ls = 0.f;
    #pragma unroll
    for (int ii = 0; ii < 16; ++ii) ls += h[ii];
    ls += __shfl_xor(ls, 1); ls += __shfl_xor(ls, 2);
    const float mu = ls * (1.f / 64.f);
    float lv = 0.f;
    #pragma unroll
    for (int ii = 0; ii < 16; ++ii){ const float d = h[ii] - mu; lv += d * d; }
    lv += __shfl_xor(lv, 1); lv += __shfl_xor(lv, 2);
    const float rs = rsqrtf(lv * (1.f / 64.f) + EPSF);
    #pragma unroll
    for (int ii = 0; ii < 16; ++ii){
      const int i = q * 16 + ii;
      const float val = (h[ii] - mu) * rs * vg[i] + vbn[i];
      // frag-packed write: s = i>>5, rt = w, lane-slot = rloc + 16*((i>>3)&3), elem = i&7
      s_hn[(((i >> 5) * 8 + w) * 64 + rloc + 16 * ((i >> 3) & 3)) * 8 + (i & 7)] = f2bf(val);
    }
  }
  __syncthreads();

  // ---------- gb MFMA: hn[128x64] @ vW2[64x1024] -> FiLM -> vfilm (frag-packed s_A) ----------
  #pragma unroll
  for (int ch = 0; ch < 2; ++ch){
    f32x4 accg[8][2], accb[8][2];
    #pragma unroll
    for (int rt = 0; rt < 8; ++rt)
      #pragma unroll
      for (int ti = 0; ti < 2; ++ti){ accg[rt][ti] = (f32x4){0,0,0,0}; accb[rt][ti] = (f32x4){0,0,0,0}; }
    #pragma unroll
    for (int s = 0; s < 2; ++s){
      bf16x8 Bgm[2], Bbm[2];
      #pragma unroll
      for (int ti = 0; ti < 2; ++ti){
        const int tp = w * 4 + ch * 2 + ti;
        Bgm[ti] = *(const bf16x8*)(vW2p + (size_t)(((s * 32 + tp) * 2 + 0) * 64 + L) * 8);
        Bbm[ti] = *(const bf16x8*)(vW2p + (size_t)(((s * 32 + tp) * 2 + 1) * 64 + L) * 8);
      }
      #pragma unroll
      for (int rt = 0; rt < 8; ++rt){
        const bf16x8 a = *(const bf16x8*)(s_hn + ((s * 8 + rt) * 64 + L) * 8);
        #pragma unroll
        for (int ti = 0; ti < 2; ++ti){
          accg[rt][ti] = __builtin_amdgcn_mfma_f32_16x16x32_bf16(a, Bgm[ti], accg[rt][ti], 0, 0, 0);
          accb[rt][ti] = __builtin_amdgcn_mfma_f32_16x16x32_bf16(a, Bbm[ti], accb[rt][ti], 0, 0, 0);
        }
      }
    }
    #pragma unroll
    for (int ti = 0; ti < 2; ++ti){
      const int n = (w * 4 + ch * 2 + ti) * 16 + al;
      const float gbias = vb2[n], bbias = vb2[512 + n];
      #pragma unroll
      for (int rt = 0; rt < 8; ++rt){
        #pragma unroll
        for (int r = 0; r < 4; ++r){
          const int z = rt * 16 + 4 * g + r;
          const float v0v = v0g[(size_t)(bz0 + z) * 512 + n];
          const float vf = v0v * (1.f + accg[rt][ti][r] + gbias) + (accb[rt][ti][r] + bbias);
          s_A[(((n >> 5) * 8 + rt) * 64 + (4 * g + r) + 16 * ((n >> 3) & 3)) * 8 + (n & 7)] = f2bf(vf);
        }
      }
    }
  }
  __syncthreads();

  // ---------- GEMM1: h2 = vfilm @ mW1 ; gelu + LN512 -> h2n (frag-packed s_A) ----------
  f32x4 acc[8][4];
  #pragma unroll
  for (int rt = 0; rt < 8; ++rt)
    #pragma unroll
    for (int ct = 0; ct < 4; ++ct) acc[rt][ct] = (f32x4){0, 0, 0, 0};
  gemm512(acc, W1p, s_A, w, L);
  {
    float mb1r[4];
    #pragma unroll
    for (int ct = 0; ct < 4; ++ct) mb1r[ct] = mb1[w * 64 + ct * 16 + al];
    // gelu + per-row partial (sum, sumsq) over this wave's 64 cols
    #pragma unroll
    for (int rt = 0; rt < 8; ++rt){
      #pragma unroll
      for (int r = 0; r < 4; ++r){
        float sv = 0.f, qv = 0.f;
        #pragma unroll
        for (int ct = 0; ct < 4; ++ct){
          const float v = gelu_f(acc[rt][ct][r] + mb1r[ct]);
          acc[rt][ct][r] = v;
          sv += v; qv += v * v;
        }
        sv += __shfl_xor(sv, 1); sv += __shfl_xor(sv, 2);
        sv += __shfl_xor(sv, 4); sv += __shfl_xor(sv, 8);
        qv += __shfl_xor(qv, 1); qv += __shfl_xor(qv, 2);
        qv += __shfl_xor(qv, 4); qv += __shfl_xor(qv, 8);
        if (al == 0){
          const int row = rt * 16 + 4 * g + r;
          s_ln[row][w][0] = sv;
          s_ln[row][w][1] = qv;
        }
      }
    }
  }
  __syncthreads();                 // all GEMM1 LDS reads done + partials visible
  if (tid < 128){
    float sv = 0.f, qv = 0.f;
    #pragma unroll
    for (int ww = 0; ww < 8; ++ww){ sv += s_ln[tid][ww][0]; qv += s_ln[tid][ww][1]; }
    const float mu = sv * (1.f / 512.f);
    s_mu[tid] = mu;
    s_rs[tid] = rsqrtf(qv * (1.f / 512.f) - mu * mu + EPSF);
  }
  __syncthreads();
  {
    float mgr[4], mbnr[4];
    #pragma unroll
    for (int ct = 0; ct < 4; ++ct){
      mgr[ct] = mg[w * 64 + ct * 16 + al];
      mbnr[ct] = mbn[w * 64 + ct * 16 + al];
    }
    #pragma unroll
    for (int rt = 0; rt < 8; ++rt){
      #pragma unroll
      for (int r = 0; r < 4; ++r){
        const int row = rt * 16 + 4 * g + r;
        const float mu = s_mu[row], rs = s_rs[row];
        #pragma unroll
        for (int ct = 0; ct < 4; ++ct){
          const int n = w * 64 + ct * 16 + al;
          const float val = (acc[rt][ct][r] - mu) * rs * mgr[ct] + mbnr[ct];
          s_A[(((n >> 5) * 8 + rt) * 64 + (4 * g + r) + 16 * ((n >> 3) & 3)) * 8 + (n & 7)] = f2bf(val);
        }
      }
    }
  }
  __syncthreads();

  // ---------- GEMM2: vfin = h2n @ mW2 ; y = sum_z att * vfin (+ mb2, since sum att = 1) ----------
  #pragma unroll
  for (int rt = 0; rt < 8; ++rt)
    #pragma unroll
    for (int ct = 0; ct < 4; ++ct) acc[rt][ct] = (f32x4){0, 0, 0, 0};
  gemm512(acc, W2p, s_A, w, L);
  {
    float yv[4] = {0.f, 0.f, 0.f, 0.f};
    #pragma unroll
    for (int rt = 0; rt < 8; ++rt){
      #pragma unroll
      for (int r = 0; r < 4; ++r){
        const float aw = s_att[w][rt * 16 + 4 * g + r];     // head of col n is exactly w
        #pragma unroll
        for (int ct = 0; ct < 4; ++ct) yv[ct] += aw * acc[rt][ct][r];
      }
    }
    #pragma unroll
    for (int ct = 0; ct < 4; ++ct){
      yv[ct] += __shfl_xor(yv[ct], 16);
      yv[ct] += __shfl_xor(yv[ct], 32);
    }
    if (g == 0){
      #pragma unroll
      for (int ct = 0; ct < 4; ++ct){
        const int n = w * 64 + ct * 16 + al;
        yout[(size_t)bc * 512 + n] = yv[ct] + mb2[n];
      }
    }
  }
}

// ---------------- K5: out = y @ Wo + bo (f32) ----------------
__global__ __launch_bounds__(256) void eca_out(
    const float* __restrict__ y, const float* __restrict__ Wo, const float* __restrict__ bo,
    float* __restrict__ out)
{
  const int rt = blockIdx.x >> 2, ct = blockIdx.x & 3;
  const int tid = threadIdx.x;
  __shared__ float s_y[32][512];
  const float* yb = y + (size_t)rt * 32 * 512;
  for (int i = tid; i < 32 * 128; i += 256)
    ((float4*)&s_y[0][0])[i] = ((const float4*)yb)[i];
  __syncthreads();
  const int jc = ct * 128 + (tid & 31) * 4;
  const int r0 = (tid >> 5) * 4;
  float acc[4][4] = {};
  #pragma unroll 4
  for (int k = 0; k < 512; ++k){
    const float4 wv = *(const float4*)(Wo + (size_t)k * 512 + jc);
    #pragma unroll
    for (int r = 0; r < 4; ++r){
      const float yv = s_y[r0 + r][k];
      acc[r][0] += yv * wv.x; acc[r][1] += yv * wv.y;
      acc[r][2] += yv * wv.z; acc[r][3] += yv * wv.w;
    }
  }
  const float4 bv4 = *(const float4*)(bo + jc);
  #pragma unroll
  for (int r = 0; r < 4; ++r){
    float4 o;
    o.x = acc[r][0] + bv4.x; o.y = acc[r][1] + bv4.y;
    o.z = acc[r][2] + bv4.z; o.w = acc[r][3] + bv4.w;
    *(float4*)(out + (size_t)(rt * 32 + r0 + r) * 512 + jc) = o;
  }
}

extern "C" void kernel_launch(void* const* d_in, const int* in_sizes, int n_in,
                              void* d_out, int out_size, void* d_ws, size_t ws_size,
                              hipStream_t stream)
{
  const float* inputs = (const float*)d_in[0];
  const float* p   = (const float*)d_in[1];
  const float* a   = (const float*)d_in[2];
  const float* Bq  = (const float*)d_in[3];
  const float* Wqe = (const float*)d_in[4];
  const float* bqe = (const float*)d_in[5];
  const float* Bv  = (const float*)d_in[6];
  const float* Wve = (const float*)d_in[7];
  const float* bve = (const float*)d_in[8];
  const float* Wq  = (const float*)d_in[9];
  const float* bq  = (const float*)d_in[10];
  const float* Wk  = (const float*)d_in[11];
  const float* bk  = (const float*)d_in[12];
  const float* Wv  = (const float*)d_in[13];
  const float* bv  = (const float*)d_in[14];
  const float* vW1 = (const float*)d_in[15];
  const float* vb1 = (const float*)d_in[16];
  const float* vg  = (const float*)d_in[17];
  const float* vbn = (const float*)d_in[18];
  const float* vW2 = (const float*)d_in[19];
  const float* vb2 = (const float*)d_in[20];
  const float* mW1 = (const float*)d_in[21];
  const float* mb1 = (const float*)d_in[22];
  const float* mg  = (const float*)d_in[23];
  const float* mbn = (const float*)d_in[24];
  const float* mW2 = (const float*)d_in[25];
  const float* mb2 = (const float*)d_in[26];
  const float* Wo  = (const float*)d_in[27];
  const float* bo  = (const float*)d_in[28];
  (void)in_sizes; (void)n_in; (void)out_size; (void)ws_size;

  float* v0g  = (float*)d_ws;                        // [2*128*512]
  float* Kqg  = v0g + 131072;                        // [2*128*512]
  float* bqkg = Kqg + 131072;                        // [2*128*8] (padded)
  float* yws  = bqkg + 2048;                         // [512*512]
  ushort_t* W1p  = (ushort_t*)(yws + 262144);        // 262144 bf16
  ushort_t* W2p  = W1p + 262144;                     // 262144 bf16
  ushort_t* vW2p = W2p + 262144;                     // 65536 bf16
  float* out = (float*)d_out;

  eca_pack<<<dim3(1024), dim3(256), 0, stream>>>(mW1, mW2, vW2, W1p, W2p, vW2p);
  eca_prep<<<dim3(NB * NZ), dim3(256), 0, stream>>>(a, Wk, bk, Wv, bv, Wq, bq, v0g, Kqg, bqkg);
  eca_main<<<dim3(NB * NC), dim3(512), 0, stream>>>(
      inputs, p, Bq, Wqe, bqe, Bv, Wve, bve, vW1, vb1, vg, vbn, vb2,
      mb1, mg, mbn, mb2, v0g, Kqg, bqkg, W1p, W2p, vW2p, yws);
  eca_out<<<dim3(64), dim3(256), 0, stream>>>(yws, Wo, bo, out);
}